// Round 11
// baseline (557.913 us; speedup 1.0000x reference)
//
#include <hip/hip_runtime.h>
#include <hip/hip_bf16.h>
#include <math.h>

#define NTOK 49      // window tokens (7x7)
#define DIMC 128     // channels
#define NHEAD 4
#define HDIM 32
#define QK_PITCH 40              // q/k row pitch (shorts): 80B rows, 16B-aligned, 2-way banks
#define Q_HEAD  (NTOK*QK_PITCH)  // 1960
#define VT_PITCH 72              // v^T row pitch (shorts): 144B rows, 16B-aligned
#define VT_HEAD (HDIM*VT_PITCH)  // 2304
#define P_PITCH 72               // P row pitch (shorts)
#define P_HEAD  (NTOK*P_PITCH)   // 3528
#define OPITCH  136              // o row pitch (shorts): 272B rows

typedef __attribute__((ext_vector_type(8))) short bf16x8;  // 8 bf16 in 4 VGPRs
typedef __attribute__((ext_vector_type(4))) float f32x4;   // MFMA C/D frag

static constexpr float SCALE = 0.17677669529663687f; // 32^-0.5

// fp32 -> bf16 (RNE) — validated numerics (r6/r10 pass)
__device__ __forceinline__ short f2bf(float f) {
    unsigned u = __float_as_uint(f);
    unsigned r = u + 0x7FFFu + ((u >> 16) & 1u);
    return (short)(r >> 16);
}

__device__ __forceinline__ bf16x8 cvt8(float4 lo, float4 hi) {
    bf16x8 v;
    v[0] = f2bf(lo.x); v[1] = f2bf(lo.y); v[2] = f2bf(lo.z); v[3] = f2bf(lo.w);
    v[4] = f2bf(hi.x); v[5] = f2bf(hi.y); v[6] = f2bf(hi.z); v[7] = f2bf(hi.w);
    return v;
}

// LDS plan (shorts; 24896 sh = 49792 B -> 3 blocks/CU, r10 was 78016 B / 2 blocks):
//   q_s : [0,     7840)  [4][49][40] bf16, pre-scaled; DEAD after QK frag reads
//   k_s : [7840, 15680)  [4][49][40] bf16;             DEAD after QK frag reads
//   v_t : [15680,24896)  [4][32][72] bf16 transposed (j=49..63 zeroed); DEAD after PV reads
//   p_s : aliases [0, 14112)  [4][49][72] bf16 probs — written AFTER the post-QK barrier;
//         per-head region is same-wave write->read only
//   o_s : aliases v_t [15680, 15680+6664) [49][136] — written AFTER the post-PV barrier
// All bases/rows 16B-aligned (15680 sh = 31360 B = 16*1960).

__global__ __launch_bounds__(256, 3)
void winattn_fused(const float* __restrict__ x,
                   const float* __restrict__ mask,
                   const float* __restrict__ qkv_w,
                   const float* __restrict__ qkv_b,
                   const float* __restrict__ proj_w,
                   const float* __restrict__ proj_b,
                   const float* __restrict__ bias_table,
                   const int*   __restrict__ rel_index,
                   float* __restrict__ out)
{
    extern __shared__ short smem[];
    short* q_s = smem;                    // [4][49][40]
    short* k_s = smem + 4*Q_HEAD;         // [4][49][40]
    short* v_t = smem + 8*Q_HEAD;         // [4][32][72]
    short* p_s = smem;                    // ALIASES q_s/k_s (safe after post-QK barrier)
    short* o_s = v_t;                     // ALIASES v_t (safe after post-PV barrier)

    const int b    = blockIdx.x;
    const int tid  = threadIdx.x;
    const int lane = tid & 63;
    const int w    = tid >> 6;       // wave 0..3
    const int lrow = lane & 15;      // MFMA fragment M/N index
    const int kgrp = lane >> 4;      // MFMA k-chunk 0..3

    const float* xb = x + (size_t)b * (NTOK * DIMC);

    // ============ Phase 1 (MFMA, validated r6): qkv = x @ qkv_w^T + qkv_b ============
    // A/B frag: row/col = lane&15, k = 8*(lane>>4)+e contiguous.
    // C/D frag: col = lane&15, row = 4*(lane>>4) + reg.
    {
        f32x4 acc[4][6];
        #pragma unroll
        for (int m = 0; m < 4; ++m)
            #pragma unroll
            for (int n = 0; n < 6; ++n)
                acc[m][n] = (f32x4){0.f, 0.f, 0.f, 0.f};

        #pragma unroll
        for (int ks = 0; ks < 4; ++ks) {
            const int k0 = 32*ks + 8*kgrp;
            bf16x8 afr[4];
            #pragma unroll
            for (int m = 0; m < 4; ++m) {
                const int r = 16*m + lrow;
                float4 lo = make_float4(0.f,0.f,0.f,0.f);
                float4 hi = make_float4(0.f,0.f,0.f,0.f);
                if (r < NTOK) {
                    lo = *reinterpret_cast<const float4*>(xb + r*DIMC + k0);
                    hi = *reinterpret_cast<const float4*>(xb + r*DIMC + k0 + 4);
                }
                afr[m] = cvt8(lo, hi);
            }
            bf16x8 bfr[6];
            #pragma unroll
            for (int n = 0; n < 6; ++n) {
                const int c = 96*w + 16*n + lrow;
                float4 lo = *reinterpret_cast<const float4*>(qkv_w + c*DIMC + k0);
                float4 hi = *reinterpret_cast<const float4*>(qkv_w + c*DIMC + k0 + 4);
                bfr[n] = cvt8(lo, hi);
            }
            #pragma unroll
            for (int m = 0; m < 4; ++m)
                #pragma unroll
                for (int n = 0; n < 6; ++n)
                    acc[m][n] = __builtin_amdgcn_mfma_f32_16x16x32_bf16(
                                    afr[m], bfr[n], acc[m][n], 0, 0, 0);
        }

        // epilogue: bias + scatter q/k (row-major) and v (TRANSPOSED, zero-padded cols 49..63)
        #pragma unroll
        for (int n = 0; n < 6; ++n) {
            const int c    = 96*w + 16*n + lrow;
            const float bi = qkv_b[c];
            const int which = c >> 7;            // 0=q 1=k 2=v
            const int hh    = (c & 127) >> 5;
            const int d     = c & 31;
            #pragma unroll
            for (int m = 0; m < 4; ++m) {
                #pragma unroll
                for (int q = 0; q < 4; ++q) {
                    const int r = 16*m + 4*kgrp + q;   // 0..63
                    const float val = acc[m][n][q] + bi;
                    if (which == 0) {
                        if (r < NTOK) q_s[hh*Q_HEAD + r*QK_PITCH + d] = f2bf(val * SCALE);
                    } else if (which == 1) {
                        if (r < NTOK) k_s[hh*Q_HEAD + r*QK_PITCH + d] = f2bf(val);
                    } else {
                        v_t[hh*VT_HEAD + d*VT_PITCH + r] = (r < NTOK) ? f2bf(val) : (short)0;
                    }
                }
            }
        }
    }
    __syncthreads();

    // ============ Phase 2 (MFMA attention, wave = head) ============
    const int h  = w;
    const int mw = b & 63;                       // mask window = b % 64
    const float* mrow = mask + (size_t)mw * (NTOK*NTOK);

    // ---- S = (q*scale) @ k^T : 4x4 tiles of 16x16, K=32 (one MFMA step) ----
    f32x4 s[4][4];
    #pragma unroll
    for (int m = 0; m < 4; ++m)
        #pragma unroll
        for (int n = 0; n < 4; ++n)
            s[m][n] = (f32x4){0.f, 0.f, 0.f, 0.f};
    {
        bf16x8 qa[4], kb[4];
        #pragma unroll
        for (int m = 0; m < 4; ++m) {
            const int r = 16*m + lrow;
            const int ii = (r < NTOK) ? r : (NTOK-1);   // clamp: dup rows, never consumed
            qa[m] = *reinterpret_cast<const bf16x8*>(q_s + h*Q_HEAD + ii*QK_PITCH + 8*kgrp);
        }
        #pragma unroll
        for (int n = 0; n < 4; ++n) {
            const int r = 16*n + lrow;
            const int jj = (r < NTOK) ? r : (NTOK-1);
            kb[n] = *reinterpret_cast<const bf16x8*>(k_s + h*Q_HEAD + jj*QK_PITCH + 8*kgrp);
        }
        #pragma unroll
        for (int m = 0; m < 4; ++m)
            #pragma unroll
            for (int n = 0; n < 4; ++n)
                s[m][n] = __builtin_amdgcn_mfma_f32_16x16x32_bf16(qa[m], kb[n], s[m][n], 0, 0, 0);
    }
    // q_s/k_s fully consumed by all waves -> p_s may overwrite them
    __syncthreads();

    // ---- + relative-position bias + shifted-window mask (j = 16n+lrow: coalesced) ----
    #pragma unroll
    for (int m = 0; m < 4; ++m) {
        #pragma unroll
        for (int q = 0; q < 4; ++q) {
            const int i = 16*m + 4*kgrp + q;
            #pragma unroll
            for (int n = 0; n < 4; ++n) {
                const int j = 16*n + lrow;
                if (i < NTOK && j < NTOK) {
                    const int ridx = rel_index[i*NTOK + j];
                    s[m][n][q] += bias_table[ridx*NHEAD + h] + mrow[i*NTOK + j];
                } else {
                    s[m][n][q] = -1e30f;   // finite "-inf": exp underflows to exactly 0
                }
            }
        }
    }

    // ---- in-register softmax over j: 4 n-regs + 4 shfl_xor steps (16 indep chains) ----
    #pragma unroll
    for (int m = 0; m < 4; ++m) {
        #pragma unroll
        for (int q = 0; q < 4; ++q) {
            float mx = fmaxf(fmaxf(s[m][0][q], s[m][1][q]), fmaxf(s[m][2][q], s[m][3][q]));
            mx = fmaxf(mx, __shfl_xor(mx, 1));
            mx = fmaxf(mx, __shfl_xor(mx, 2));
            mx = fmaxf(mx, __shfl_xor(mx, 4));
            mx = fmaxf(mx, __shfl_xor(mx, 8));
            float sum = 0.f;
            #pragma unroll
            for (int n = 0; n < 4; ++n) {
                const float e = __expf(s[m][n][q] - mx);
                s[m][n][q] = e;
                sum += e;
            }
            sum += __shfl_xor(sum, 1);
            sum += __shfl_xor(sum, 2);
            sum += __shfl_xor(sum, 4);
            sum += __shfl_xor(sum, 8);
            const float inv = __builtin_amdgcn_rcpf(sum);
            const int i = 16*m + 4*kgrp + q;
            if (i < NTOK) {
                #pragma unroll
                for (int n = 0; n < 4; ++n)
                    p_s[h*P_HEAD + i*P_PITCH + 16*n + lrow] = f2bf(s[m][n][q] * inv);
            }
        }
    }
    // (per-head p region: same-wave write->read; compiler inserts lgkmcnt wait)

    // ---- O = P @ V : A=P rows i, B=v_t rows d, K=j in 2 steps of 32 ----
    f32x4 o[4][2];
    #pragma unroll
    for (int m = 0; m < 4; ++m)
        #pragma unroll
        for (int n = 0; n < 2; ++n)
            o[m][n] = (f32x4){0.f, 0.f, 0.f, 0.f};
    #pragma unroll
    for (int ks = 0; ks < 2; ++ks) {
        bf16x8 pa[4], vb[2];
        #pragma unroll
        for (int m = 0; m < 4; ++m) {
            const int r = 16*m + lrow;
            const int ii = (r < NTOK) ? r : (NTOK-1);
            pa[m] = *reinterpret_cast<const bf16x8*>(p_s + h*P_HEAD + ii*P_PITCH + 32*ks + 8*kgrp);
        }
        #pragma unroll
        for (int n = 0; n < 2; ++n) {
            const int d = 16*n + lrow;   // 0..31 exact
            vb[n] = *reinterpret_cast<const bf16x8*>(v_t + h*VT_HEAD + d*VT_PITCH + 32*ks + 8*kgrp);
        }
        #pragma unroll
        for (int m = 0; m < 4; ++m)
            #pragma unroll
            for (int n = 0; n < 2; ++n)
                o[m][n] = __builtin_amdgcn_mfma_f32_16x16x32_bf16(pa[m], vb[n], o[m][n], 0, 0, 0);
    }

    __syncthreads();   // all waves done reading v_t (and p_s) before o_s (alias of v_t) is written

    #pragma unroll
    for (int n = 0; n < 2; ++n) {
        #pragma unroll
        for (int m = 0; m < 4; ++m) {
            #pragma unroll
            for (int q = 0; q < 4; ++q) {
                const int i = 16*m + 4*kgrp + q;
                if (i < NTOK)
                    o_s[i*OPITCH + h*HDIM + 16*n + lrow] = f2bf(o[m][n][q]);
            }
        }
    }
    __syncthreads();

    // ============ Phase 3 (MFMA, validated r6): out = o @ proj_w^T + proj_b ============
    {
        f32x4 pacc[4][2];
        #pragma unroll
        for (int m = 0; m < 4; ++m)
            #pragma unroll
            for (int n = 0; n < 2; ++n)
                pacc[m][n] = (f32x4){0.f, 0.f, 0.f, 0.f};

        #pragma unroll
        for (int ks = 0; ks < 4; ++ks) {
            const int k0 = 32*ks + 8*kgrp;
            bf16x8 afr[4];
            #pragma unroll
            for (int m = 0; m < 4; ++m) {
                const int r = 16*m + lrow;
                const int rr = (r < NTOK) ? r : 0;
                afr[m] = *reinterpret_cast<const bf16x8*>(o_s + rr*OPITCH + k0);
            }
            bf16x8 bfr[2];
            #pragma unroll
            for (int n = 0; n < 2; ++n) {
                const int c = 32*w + 16*n + lrow;
                float4 lo = *reinterpret_cast<const float4*>(proj_w + c*DIMC + k0);
                float4 hi = *reinterpret_cast<const float4*>(proj_w + c*DIMC + k0 + 4);
                bfr[n] = cvt8(lo, hi);
            }
            #pragma unroll
            for (int m = 0; m < 4; ++m)
                #pragma unroll
                for (int n = 0; n < 2; ++n)
                    pacc[m][n] = __builtin_amdgcn_mfma_f32_16x16x32_bf16(
                                     afr[m], bfr[n], pacc[m][n], 0, 0, 0);
        }

        float* ob = out + (size_t)b * (NTOK * DIMC);
        #pragma unroll
        for (int n = 0; n < 2; ++n) {
            const int c    = 32*w + 16*n + lrow;
            const float bi = proj_b[c];
            #pragma unroll
            for (int m = 0; m < 4; ++m) {
                #pragma unroll
                for (int q = 0; q < 4; ++q) {
                    const int r = 16*m + 4*kgrp + q;
                    if (r < NTOK) ob[r*DIMC + c] = pacc[m][n][q] + bi;
                }
            }
        }
    }
}

extern "C" void kernel_launch(void* const* d_in, const int* in_sizes, int n_in,
                              void* d_out, int out_size, void* d_ws, size_t ws_size,
                              hipStream_t stream) {
    const float* x      = (const float*)d_in[0];
    const float* mask   = (const float*)d_in[1];
    const float* qkv_w  = (const float*)d_in[2];
    const float* qkv_b  = (const float*)d_in[3];
    const float* proj_w = (const float*)d_in[4];
    const float* proj_b = (const float*)d_in[5];
    const float* tbl    = (const float*)d_in[6];
    const int*   ridx   = (const int*)d_in[7];
    float* out = (float*)d_out;

    const int B = in_sizes[0] / (NTOK * DIMC);   // 4096 windows
    const size_t shmem = 49792;                  // bytes (< 64KB: no attr call needed)

    winattn_fused<<<B, 256, shmem, stream>>>(x, mask, qkv_w, qkv_b,
                                             proj_w, proj_b, tbl, ridx, out);
}

// Round 12
// 448.449 us; speedup vs baseline: 1.2441x; 1.2441x over previous
//
#include <hip/hip_runtime.h>
#include <hip/hip_bf16.h>
#include <math.h>

#define NTOK 49      // window tokens (7x7)
#define DIMC 128     // channels
#define NHEAD 4
#define HDIM 32
#define QK_PITCH 40              // q/k row pitch (shorts): 80B rows, 16B-aligned, 2-way banks
#define Q_HEAD  (NTOK*QK_PITCH)  // 1960
#define VT_PITCH 72              // v^T row pitch (shorts): 144B rows, 16B-aligned
#define VT_HEAD (HDIM*VT_PITCH)  // 2304
#define P_PITCH 72               // P row pitch (shorts)
#define P_HEAD  (NTOK*P_PITCH)   // 3528
#define OPITCH  136              // o row pitch (shorts): 272B rows

typedef __attribute__((ext_vector_type(8))) short bf16x8;  // 8 bf16 in 4 VGPRs
typedef __attribute__((ext_vector_type(4))) float f32x4;   // MFMA C/D frag

static constexpr float SCALE = 0.17677669529663687f; // 32^-0.5

// fp32 -> bf16 (RNE) — validated numerics (r6/r10/r11 pass)
__device__ __forceinline__ short f2bf(float f) {
    unsigned u = __float_as_uint(f);
    unsigned r = u + 0x7FFFu + ((u >> 16) & 1u);
    return (short)(r >> 16);
}

__device__ __forceinline__ bf16x8 cvt8(float4 lo, float4 hi) {
    bf16x8 v;
    v[0] = f2bf(lo.x); v[1] = f2bf(lo.y); v[2] = f2bf(lo.z); v[3] = f2bf(lo.w);
    v[4] = f2bf(hi.x); v[5] = f2bf(hi.y); v[6] = f2bf(hi.z); v[7] = f2bf(hi.w);
    return v;
}

// LDS plan (shorts; 24896 sh = 49792 B -> 3 blocks/CU at VGPR=108):
//   q_s : [0,     7840)  [4][49][40] bf16, pre-scaled; DEAD after QK frag reads
//   k_s : [7840, 15680)  [4][49][40] bf16;             DEAD after QK frag reads
//   v_t : [15680,24896)  [4][32][72] bf16 transposed (j=49..63 zeroed); DEAD after PV reads
//   p_s : aliases [0, 14112)  [4][49][72] bf16 probs — written AFTER the post-QK barrier
//   o_s : aliases v_t [15680, +6664) [49][136] — written AFTER the post-PV barrier
// Alias plan validated on HW (r11 passed).
//
// NOTE on launch_bounds: (256,3) in r11 forced VGPR 108->84 and SPILLED
// (FETCH 52->301MB, WRITE 100->608MB, dur 327->440us). (256,2) restores the
// natural no-spill allocation; 3 blocks/CU still resident (LDS-limited).

__global__ __launch_bounds__(256, 2)
void winattn_fused(const float* __restrict__ x,
                   const float* __restrict__ mask,
                   const float* __restrict__ qkv_w,
                   const float* __restrict__ qkv_b,
                   const float* __restrict__ proj_w,
                   const float* __restrict__ proj_b,
                   const float* __restrict__ bias_table,
                   const int*   __restrict__ rel_index,
                   float* __restrict__ out)
{
    extern __shared__ short smem[];
    short* q_s = smem;                    // [4][49][40]
    short* k_s = smem + 4*Q_HEAD;         // [4][49][40]
    short* v_t = smem + 8*Q_HEAD;         // [4][32][72]
    short* p_s = smem;                    // ALIASES q_s/k_s (safe after post-QK barrier)
    short* o_s = v_t;                     // ALIASES v_t (safe after post-PV barrier)

    const int b    = blockIdx.x;
    const int tid  = threadIdx.x;
    const int lane = tid & 63;
    const int w    = tid >> 6;       // wave 0..3
    const int lrow = lane & 15;      // MFMA fragment M/N index
    const int kgrp = lane >> 4;      // MFMA k-chunk 0..3

    const float* xb = x + (size_t)b * (NTOK * DIMC);

    // ============ Phase 1 (MFMA, validated r6): qkv = x @ qkv_w^T + qkv_b ============
    // A/B frag: row/col = lane&15, k = 8*(lane>>4)+e contiguous.
    // C/D frag: col = lane&15, row = 4*(lane>>4) + reg.
    {
        f32x4 acc[4][6];
        #pragma unroll
        for (int m = 0; m < 4; ++m)
            #pragma unroll
            for (int n = 0; n < 6; ++n)
                acc[m][n] = (f32x4){0.f, 0.f, 0.f, 0.f};

        #pragma unroll
        for (int ks = 0; ks < 4; ++ks) {
            const int k0 = 32*ks + 8*kgrp;
            bf16x8 afr[4];
            #pragma unroll
            for (int m = 0; m < 4; ++m) {
                const int r = 16*m + lrow;
                float4 lo = make_float4(0.f,0.f,0.f,0.f);
                float4 hi = make_float4(0.f,0.f,0.f,0.f);
                if (r < NTOK) {
                    lo = *reinterpret_cast<const float4*>(xb + r*DIMC + k0);
                    hi = *reinterpret_cast<const float4*>(xb + r*DIMC + k0 + 4);
                }
                afr[m] = cvt8(lo, hi);
            }
            bf16x8 bfr[6];
            #pragma unroll
            for (int n = 0; n < 6; ++n) {
                const int c = 96*w + 16*n + lrow;
                float4 lo = *reinterpret_cast<const float4*>(qkv_w + c*DIMC + k0);
                float4 hi = *reinterpret_cast<const float4*>(qkv_w + c*DIMC + k0 + 4);
                bfr[n] = cvt8(lo, hi);
            }
            #pragma unroll
            for (int m = 0; m < 4; ++m)
                #pragma unroll
                for (int n = 0; n < 6; ++n)
                    acc[m][n] = __builtin_amdgcn_mfma_f32_16x16x32_bf16(
                                    afr[m], bfr[n], acc[m][n], 0, 0, 0);
        }

        // epilogue: bias + scatter q/k (row-major) and v (TRANSPOSED, zero-padded cols 49..63)
        #pragma unroll
        for (int n = 0; n < 6; ++n) {
            const int c    = 96*w + 16*n + lrow;
            const float bi = qkv_b[c];
            const int which = c >> 7;            // 0=q 1=k 2=v
            const int hh    = (c & 127) >> 5;
            const int d     = c & 31;
            #pragma unroll
            for (int m = 0; m < 4; ++m) {
                #pragma unroll
                for (int q = 0; q < 4; ++q) {
                    const int r = 16*m + 4*kgrp + q;   // 0..63
                    const float val = acc[m][n][q] + bi;
                    if (which == 0) {
                        if (r < NTOK) q_s[hh*Q_HEAD + r*QK_PITCH + d] = f2bf(val * SCALE);
                    } else if (which == 1) {
                        if (r < NTOK) k_s[hh*Q_HEAD + r*QK_PITCH + d] = f2bf(val);
                    } else {
                        v_t[hh*VT_HEAD + d*VT_PITCH + r] = (r < NTOK) ? f2bf(val) : (short)0;
                    }
                }
            }
        }
    }
    __syncthreads();

    // ============ Phase 2 (MFMA attention, wave = head) ============
    const int h  = w;
    const int mw = b & 63;                       // mask window = b % 64
    const float* mrow = mask + (size_t)mw * (NTOK*NTOK);

    // ---- S = (q*scale) @ k^T : 4x4 tiles of 16x16, K=32 (one MFMA step) ----
    f32x4 s[4][4];
    #pragma unroll
    for (int m = 0; m < 4; ++m)
        #pragma unroll
        for (int n = 0; n < 4; ++n)
            s[m][n] = (f32x4){0.f, 0.f, 0.f, 0.f};
    {
        bf16x8 qa[4], kb[4];
        #pragma unroll
        for (int m = 0; m < 4; ++m) {
            const int r = 16*m + lrow;
            const int ii = (r < NTOK) ? r : (NTOK-1);   // clamp: dup rows, never consumed
            qa[m] = *reinterpret_cast<const bf16x8*>(q_s + h*Q_HEAD + ii*QK_PITCH + 8*kgrp);
        }
        #pragma unroll
        for (int n = 0; n < 4; ++n) {
            const int r = 16*n + lrow;
            const int jj = (r < NTOK) ? r : (NTOK-1);
            kb[n] = *reinterpret_cast<const bf16x8*>(k_s + h*Q_HEAD + jj*QK_PITCH + 8*kgrp);
        }
        #pragma unroll
        for (int m = 0; m < 4; ++m)
            #pragma unroll
            for (int n = 0; n < 4; ++n)
                s[m][n] = __builtin_amdgcn_mfma_f32_16x16x32_bf16(qa[m], kb[n], s[m][n], 0, 0, 0);
    }
    // q_s/k_s fully consumed by all waves -> p_s may overwrite them
    __syncthreads();

    // ---- + relative-position bias + shifted-window mask (j = 16n+lrow: coalesced) ----
    #pragma unroll
    for (int m = 0; m < 4; ++m) {
        #pragma unroll
        for (int q = 0; q < 4; ++q) {
            const int i = 16*m + 4*kgrp + q;
            #pragma unroll
            for (int n = 0; n < 4; ++n) {
                const int j = 16*n + lrow;
                if (i < NTOK && j < NTOK) {
                    const int ridx = rel_index[i*NTOK + j];
                    s[m][n][q] += bias_table[ridx*NHEAD + h] + mrow[i*NTOK + j];
                } else {
                    s[m][n][q] = -1e30f;   // finite "-inf": exp underflows to exactly 0
                }
            }
        }
    }

    // ---- in-register softmax over j: 4 n-regs + 4 shfl_xor steps (16 indep chains) ----
    #pragma unroll
    for (int m = 0; m < 4; ++m) {
        #pragma unroll
        for (int q = 0; q < 4; ++q) {
            float mx = fmaxf(fmaxf(s[m][0][q], s[m][1][q]), fmaxf(s[m][2][q], s[m][3][q]));
            mx = fmaxf(mx, __shfl_xor(mx, 1));
            mx = fmaxf(mx, __shfl_xor(mx, 2));
            mx = fmaxf(mx, __shfl_xor(mx, 4));
            mx = fmaxf(mx, __shfl_xor(mx, 8));
            float sum = 0.f;
            #pragma unroll
            for (int n = 0; n < 4; ++n) {
                const float e = __expf(s[m][n][q] - mx);
                s[m][n][q] = e;
                sum += e;
            }
            sum += __shfl_xor(sum, 1);
            sum += __shfl_xor(sum, 2);
            sum += __shfl_xor(sum, 4);
            sum += __shfl_xor(sum, 8);
            const float inv = __builtin_amdgcn_rcpf(sum);
            const int i = 16*m + 4*kgrp + q;
            if (i < NTOK) {
                #pragma unroll
                for (int n = 0; n < 4; ++n)
                    p_s[h*P_HEAD + i*P_PITCH + 16*n + lrow] = f2bf(s[m][n][q] * inv);
            }
        }
    }
    // (per-head p region: same-wave write->read; compiler inserts lgkmcnt wait)

    // ---- O = P @ V : A=P rows i, B=v_t rows d, K=j in 2 steps of 32 ----
    f32x4 o[4][2];
    #pragma unroll
    for (int m = 0; m < 4; ++m)
        #pragma unroll
        for (int n = 0; n < 2; ++n)
            o[m][n] = (f32x4){0.f, 0.f, 0.f, 0.f};
    #pragma unroll
    for (int ks = 0; ks < 2; ++ks) {
        bf16x8 pa[4], vb[2];
        #pragma unroll
        for (int m = 0; m < 4; ++m) {
            const int r = 16*m + lrow;
            const int ii = (r < NTOK) ? r : (NTOK-1);
            pa[m] = *reinterpret_cast<const bf16x8*>(p_s + h*P_HEAD + ii*P_PITCH + 32*ks + 8*kgrp);
        }
        #pragma unroll
        for (int n = 0; n < 2; ++n) {
            const int d = 16*n + lrow;   // 0..31 exact
            vb[n] = *reinterpret_cast<const bf16x8*>(v_t + h*VT_HEAD + d*VT_PITCH + 32*ks + 8*kgrp);
        }
        #pragma unroll
        for (int m = 0; m < 4; ++m)
            #pragma unroll
            for (int n = 0; n < 2; ++n)
                o[m][n] = __builtin_amdgcn_mfma_f32_16x16x32_bf16(pa[m], vb[n], o[m][n], 0, 0, 0);
    }

    __syncthreads();   // all waves done reading v_t (and p_s) before o_s (alias of v_t) is written

    #pragma unroll
    for (int n = 0; n < 2; ++n) {
        #pragma unroll
        for (int m = 0; m < 4; ++m) {
            #pragma unroll
            for (int q = 0; q < 4; ++q) {
                const int i = 16*m + 4*kgrp + q;
                if (i < NTOK)
                    o_s[i*OPITCH + h*HDIM + 16*n + lrow] = f2bf(o[m][n][q]);
            }
        }
    }
    __syncthreads();

    // ============ Phase 3 (MFMA, validated r6): out = o @ proj_w^T + proj_b ============
    {
        f32x4 pacc[4][2];
        #pragma unroll
        for (int m = 0; m < 4; ++m)
            #pragma unroll
            for (int n = 0; n < 2; ++n)
                pacc[m][n] = (f32x4){0.f, 0.f, 0.f, 0.f};

        #pragma unroll
        for (int ks = 0; ks < 4; ++ks) {
            const int k0 = 32*ks + 8*kgrp;
            bf16x8 afr[4];
            #pragma unroll
            for (int m = 0; m < 4; ++m) {
                const int r = 16*m + lrow;
                const int rr = (r < NTOK) ? r : 0;
                afr[m] = *reinterpret_cast<const bf16x8*>(o_s + rr*OPITCH + k0);
            }
            bf16x8 bfr[2];
            #pragma unroll
            for (int n = 0; n < 2; ++n) {
                const int c = 32*w + 16*n + lrow;
                float4 lo = *reinterpret_cast<const float4*>(proj_w + c*DIMC + k0);
                float4 hi = *reinterpret_cast<const float4*>(proj_w + c*DIMC + k0 + 4);
                bfr[n] = cvt8(lo, hi);
            }
            #pragma unroll
            for (int m = 0; m < 4; ++m)
                #pragma unroll
                for (int n = 0; n < 2; ++n)
                    pacc[m][n] = __builtin_amdgcn_mfma_f32_16x16x32_bf16(
                                     afr[m], bfr[n], pacc[m][n], 0, 0, 0);
        }

        float* ob = out + (size_t)b * (NTOK * DIMC);
        #pragma unroll
        for (int n = 0; n < 2; ++n) {
            const int c    = 32*w + 16*n + lrow;
            const float bi = proj_b[c];
            #pragma unroll
            for (int m = 0; m < 4; ++m) {
                #pragma unroll
                for (int q = 0; q < 4; ++q) {
                    const int r = 16*m + 4*kgrp + q;
                    if (r < NTOK) ob[r*DIMC + c] = pacc[m][n][q] + bi;
                }
            }
        }
    }
}

extern "C" void kernel_launch(void* const* d_in, const int* in_sizes, int n_in,
                              void* d_out, int out_size, void* d_ws, size_t ws_size,
                              hipStream_t stream) {
    const float* x      = (const float*)d_in[0];
    const float* mask   = (const float*)d_in[1];
    const float* qkv_w  = (const float*)d_in[2];
    const float* qkv_b  = (const float*)d_in[3];
    const float* proj_w = (const float*)d_in[4];
    const float* proj_b = (const float*)d_in[5];
    const float* tbl    = (const float*)d_in[6];
    const int*   ridx   = (const int*)d_in[7];
    float* out = (float*)d_out;

    const int B = in_sizes[0] / (NTOK * DIMC);   // 4096 windows
    const size_t shmem = 49792;                  // bytes (< 64KB: no attr call needed)

    winattn_fused<<<B, 256, shmem, stream>>>(x, mask, qkv_w, qkv_b,
                                             proj_w, proj_b, tbl, ridx, out);
}

// Round 14
// 394.181 us; speedup vs baseline: 1.4154x; 1.1377x over previous
//
#include <hip/hip_runtime.h>
#include <hip/hip_bf16.h>
#include <math.h>

#define NTOK 49      // window tokens (7x7)
#define DIMC 128     // channels
#define NHEAD 4
#define HDIM 32
#define QK_PITCH 40              // q/k row pitch (shorts): 80B rows, 16B-aligned, 2-way banks
#define Q_HEAD  (NTOK*QK_PITCH)  // 1960
#define VT_PITCH 72              // v^T row pitch (shorts): 144B rows, 16B-aligned
#define VT_HEAD (HDIM*VT_PITCH)  // 2304
#define P_PITCH 72               // P row pitch (shorts)
#define P_HEAD  (NTOK*P_PITCH)   // 3528
#define OPITCH  136              // o row pitch (shorts): 272B rows

#define WBF_QKV 0                // d_ws layout: qkv_w bf16 [384*128]
#define WBF_PROJ 49152           //              proj_w bf16 [128*128]
#define WBF_BYTES 131072         // (49152+16384)*2

typedef __attribute__((ext_vector_type(8))) short bf16x8;  // 8 bf16 in 4 VGPRs
typedef __attribute__((ext_vector_type(4))) short short4v;
typedef __attribute__((ext_vector_type(4))) float f32x4;   // MFMA C/D frag

static constexpr float SCALE = 0.17677669529663687f; // 32^-0.5

// fp32 -> bf16 via HW cvt (RNE — numerically identical to the r6-validated
// integer RNE, but 1 op/value and the compiler packs pairs into
// v_cvt_pk_bf16_f32). [r12 lesson: hand-rolled integer RNE was 4 ops/value
// and ~55% of all VALU issue.]
__device__ __forceinline__ short bf(float f) {
    __hip_bfloat16 h = __float2bfloat16(f);
    return __builtin_bit_cast(short, h);
}

__device__ __forceinline__ bf16x8 cvt8(float4 lo, float4 hi) {
    bf16x8 v;
    v[0] = bf(lo.x); v[1] = bf(lo.y); v[2] = bf(lo.z); v[3] = bf(lo.w);
    v[4] = bf(hi.x); v[5] = bf(hi.y); v[6] = bf(hi.z); v[7] = bf(hi.w);
    return v;
}

// One-shot weight conversion: qkv_w (12288 float4) + proj_w (4096 float4) -> bf16 in d_ws.
__global__ __launch_bounds__(256)
void convert_weights(const float* __restrict__ qkv_w,
                     const float* __restrict__ proj_w,
                     short* __restrict__ wbf)
{
    const int i = blockIdx.x * 256 + threadIdx.x;   // 0..16383 float4s
    float4 v = (i < 12288) ? reinterpret_cast<const float4*>(qkv_w)[i]
                           : reinterpret_cast<const float4*>(proj_w)[i - 12288];
    short4v s;
    s[0] = bf(v.x); s[1] = bf(v.y); s[2] = bf(v.z); s[3] = bf(v.w);
    reinterpret_cast<short4v*>(wbf)[i] = s;
}

// LDS plan (shorts; 24896 sh = 49792 B):
//   q_s : [0,     7840)  [4][49][40] bf16, pre-scaled; DEAD after QK frag reads
//   k_s : [7840, 15680)  [4][49][40] bf16;             DEAD after QK frag reads
//   v_t : [15680,24896)  [4][32][72] bf16 transposed (j=49..63 zeroed); DEAD after PV reads
//   p_s : aliases [0, 14112)  [4][49][72] bf16 probs — written AFTER the post-QK barrier
//   o_s : aliases v_t [15680, +6664) [49][136] — written AFTER the post-PV barrier
//
// Occupancy journal: residency is 2 blocks/CU bound by UNIFIED VGPR+AGPR
// (~210/wave incl. 96 acc regs), NOT LDS (r10 vs r12 identical counters at
// 78KB vs 49.8KB). launch_bounds(256,3) forces spills (r11: +850MB scratch
// traffic, dur 327->440). Keep (256,2).

template<bool PRE>
__global__ __launch_bounds__(256, 2)
void winattn_fused(const float* __restrict__ x,
                   const float* __restrict__ mask,
                   const float* __restrict__ qkv_w,
                   const float* __restrict__ qkv_b,
                   const float* __restrict__ proj_w,
                   const float* __restrict__ proj_b,
                   const float* __restrict__ bias_table,
                   const int*   __restrict__ rel_index,
                   const short* __restrict__ wbf,
                   float* __restrict__ out)
{
    extern __shared__ short smem[];
    short* q_s = smem;                    // [4][49][40]
    short* k_s = smem + 4*Q_HEAD;         // [4][49][40]
    short* v_t = smem + 8*Q_HEAD;         // [4][32][72]
    short* p_s = smem;                    // ALIASES q_s/k_s (safe after post-QK barrier)
    short* o_s = v_t;                     // ALIASES v_t (safe after post-PV barrier)

    const int b    = blockIdx.x;
    const int tid  = threadIdx.x;
    const int lane = tid & 63;
    const int w    = tid >> 6;       // wave 0..3
    const int lrow = lane & 15;      // MFMA fragment M/N index
    const int kgrp = lane >> 4;      // MFMA k-chunk 0..3

    const float* xb = x + (size_t)b * (NTOK * DIMC);

    // ============ Phase 1 (MFMA, validated r6): qkv = x @ qkv_w^T + qkv_b ============
    // A/B frag: row/col = lane&15, k = 8*(lane>>4)+e contiguous.
    // C/D frag: col = lane&15, row = 4*(lane>>4) + reg.
    {
        f32x4 acc[4][6];
        #pragma unroll
        for (int m = 0; m < 4; ++m)
            #pragma unroll
            for (int n = 0; n < 6; ++n)
                acc[m][n] = (f32x4){0.f, 0.f, 0.f, 0.f};

        #pragma unroll
        for (int ks = 0; ks < 4; ++ks) {
            const int k0 = 32*ks + 8*kgrp;
            bf16x8 afr[4];
            #pragma unroll
            for (int m = 0; m < 4; ++m) {
                const int r = 16*m + lrow;
                float4 lo = make_float4(0.f,0.f,0.f,0.f);
                float4 hi = make_float4(0.f,0.f,0.f,0.f);
                if (r < NTOK) {
                    lo = *reinterpret_cast<const float4*>(xb + r*DIMC + k0);
                    hi = *reinterpret_cast<const float4*>(xb + r*DIMC + k0 + 4);
                }
                afr[m] = cvt8(lo, hi);
            }
            bf16x8 bfr[6];
            #pragma unroll
            for (int n = 0; n < 6; ++n) {
                const int c = 96*w + 16*n + lrow;
                if (PRE) {
                    bfr[n] = *reinterpret_cast<const bf16x8*>(wbf + WBF_QKV + c*DIMC + k0);
                } else {
                    float4 lo = *reinterpret_cast<const float4*>(qkv_w + c*DIMC + k0);
                    float4 hi = *reinterpret_cast<const float4*>(qkv_w + c*DIMC + k0 + 4);
                    bfr[n] = cvt8(lo, hi);
                }
            }
            #pragma unroll
            for (int m = 0; m < 4; ++m)
                #pragma unroll
                for (int n = 0; n < 6; ++n)
                    acc[m][n] = __builtin_amdgcn_mfma_f32_16x16x32_bf16(
                                    afr[m], bfr[n], acc[m][n], 0, 0, 0);
        }

        // epilogue: bias + scatter q/k (row-major) and v (TRANSPOSED, zero-padded cols 49..63)
        #pragma unroll
        for (int n = 0; n < 6; ++n) {
            const int c    = 96*w + 16*n + lrow;
            const float bi = qkv_b[c];
            const int which = c >> 7;            // 0=q 1=k 2=v
            const int hh    = (c & 127) >> 5;
            const int d     = c & 31;
            #pragma unroll
            for (int m = 0; m < 4; ++m) {
                #pragma unroll
                for (int q = 0; q < 4; ++q) {
                    const int r = 16*m + 4*kgrp + q;   // 0..63
                    const float val = acc[m][n][q] + bi;
                    if (which == 0) {
                        if (r < NTOK) q_s[hh*Q_HEAD + r*QK_PITCH + d] = bf(val * SCALE);
                    } else if (which == 1) {
                        if (r < NTOK) k_s[hh*Q_HEAD + r*QK_PITCH + d] = bf(val);
                    } else {
                        v_t[hh*VT_HEAD + d*VT_PITCH + r] = (r < NTOK) ? bf(val) : (short)0;
                    }
                }
            }
        }
    }
    __syncthreads();

    // ============ Phase 2 (MFMA attention, wave = head) ============
    const int h  = w;
    const int mw = b & 63;                       // mask window = b % 64
    const float* mrow = mask + (size_t)mw * (NTOK*NTOK);

    // ---- S = (q*scale) @ k^T : 4x4 tiles of 16x16, K=32 (one MFMA step) ----
    f32x4 s[4][4];
    #pragma unroll
    for (int m = 0; m < 4; ++m)
        #pragma unroll
        for (int n = 0; n < 4; ++n)
            s[m][n] = (f32x4){0.f, 0.f, 0.f, 0.f};
    {
        bf16x8 qa[4], kb[4];
        #pragma unroll
        for (int m = 0; m < 4; ++m) {
            const int r = 16*m + lrow;
            const int ii = (r < NTOK) ? r : (NTOK-1);   // clamp: dup rows, never consumed
            qa[m] = *reinterpret_cast<const bf16x8*>(q_s + h*Q_HEAD + ii*QK_PITCH + 8*kgrp);
        }
        #pragma unroll
        for (int n = 0; n < 4; ++n) {
            const int r = 16*n + lrow;
            const int jj = (r < NTOK) ? r : (NTOK-1);
            kb[n] = *reinterpret_cast<const bf16x8*>(k_s + h*Q_HEAD + jj*QK_PITCH + 8*kgrp);
        }
        #pragma unroll
        for (int m = 0; m < 4; ++m)
            #pragma unroll
            for (int n = 0; n < 4; ++n)
                s[m][n] = __builtin_amdgcn_mfma_f32_16x16x32_bf16(qa[m], kb[n], s[m][n], 0, 0, 0);
    }
    // q_s/k_s fully consumed by all waves -> p_s may overwrite them
    __syncthreads();

    // ---- + relative-position bias + shifted-window mask (j = 16n+lrow: coalesced) ----
    #pragma unroll
    for (int m = 0; m < 4; ++m) {
        #pragma unroll
        for (int q = 0; q < 4; ++q) {
            const int i = 16*m + 4*kgrp + q;
            #pragma unroll
            for (int n = 0; n < 4; ++n) {
                const int j = 16*n + lrow;
                if (i < NTOK && j < NTOK) {
                    const int ridx = rel_index[i*NTOK + j];
                    s[m][n][q] += bias_table[ridx*NHEAD + h] + mrow[i*NTOK + j];
                } else {
                    s[m][n][q] = -1e30f;   // finite "-inf": exp underflows to exactly 0
                }
            }
        }
    }

    // ---- in-register softmax over j: 4 n-regs + 4 shfl_xor steps (16 indep chains) ----
    #pragma unroll
    for (int m = 0; m < 4; ++m) {
        #pragma unroll
        for (int q = 0; q < 4; ++q) {
            float mx = fmaxf(fmaxf(s[m][0][q], s[m][1][q]), fmaxf(s[m][2][q], s[m][3][q]));
            mx = fmaxf(mx, __shfl_xor(mx, 1));
            mx = fmaxf(mx, __shfl_xor(mx, 2));
            mx = fmaxf(mx, __shfl_xor(mx, 4));
            mx = fmaxf(mx, __shfl_xor(mx, 8));
            float sum = 0.f;
            #pragma unroll
            for (int n = 0; n < 4; ++n) {
                const float e = __expf(s[m][n][q] - mx);
                s[m][n][q] = e;
                sum += e;
            }
            sum += __shfl_xor(sum, 1);
            sum += __shfl_xor(sum, 2);
            sum += __shfl_xor(sum, 4);
            sum += __shfl_xor(sum, 8);
            const float inv = __builtin_amdgcn_rcpf(sum);
            const int i = 16*m + 4*kgrp + q;
            if (i < NTOK) {
                #pragma unroll
                for (int n = 0; n < 4; ++n)
                    p_s[h*P_HEAD + i*P_PITCH + 16*n + lrow] = bf(s[m][n][q] * inv);
            }
        }
    }
    // (per-head p region: same-wave write->read; compiler inserts lgkmcnt wait)

    // ---- O = P @ V : A=P rows i, B=v_t rows d, K=j in 2 steps of 32 ----
    f32x4 o[4][2];
    #pragma unroll
    for (int m = 0; m < 4; ++m)
        #pragma unroll
        for (int n = 0; n < 2; ++n)
            o[m][n] = (f32x4){0.f, 0.f, 0.f, 0.f};
    #pragma unroll
    for (int ks = 0; ks < 2; ++ks) {
        bf16x8 pa[4], vb[2];
        #pragma unroll
        for (int m = 0; m < 4; ++m) {
            const int r = 16*m + lrow;
            const int ii = (r < NTOK) ? r : (NTOK-1);
            pa[m] = *reinterpret_cast<const bf16x8*>(p_s + h*P_HEAD + ii*P_PITCH + 32*ks + 8*kgrp);
        }
        #pragma unroll
        for (int n = 0; n < 2; ++n) {
            const int d = 16*n + lrow;   // 0..31 exact
            vb[n] = *reinterpret_cast<const bf16x8*>(v_t + h*VT_HEAD + d*VT_PITCH + 32*ks + 8*kgrp);
        }
        #pragma unroll
        for (int m = 0; m < 4; ++m)
            #pragma unroll
            for (int n = 0; n < 2; ++n)
                o[m][n] = __builtin_amdgcn_mfma_f32_16x16x32_bf16(pa[m], vb[n], o[m][n], 0, 0, 0);
    }

    __syncthreads();   // all waves done reading v_t (and p_s) before o_s (alias of v_t) is written

    #pragma unroll
    for (int n = 0; n < 2; ++n) {
        #pragma unroll
        for (int m = 0; m < 4; ++m) {
            #pragma unroll
            for (int q = 0; q < 4; ++q) {
                const int i = 16*m + 4*kgrp + q;
                if (i < NTOK)
                    o_s[i*OPITCH + h*HDIM + 16*n + lrow] = bf(o[m][n][q]);
            }
        }
    }
    __syncthreads();

    // ============ Phase 3 (MFMA, validated r6): out = o @ proj_w^T + proj_b ============
    {
        f32x4 pacc[4][2];
        #pragma unroll
        for (int m = 0; m < 4; ++m)
            #pragma unroll
            for (int n = 0; n < 2; ++n)
                pacc[m][n] = (f32x4){0.f, 0.f, 0.f, 0.f};

        #pragma unroll
        for (int ks = 0; ks < 4; ++ks) {
            const int k0 = 32*ks + 8*kgrp;
            bf16x8 afr[4];
            #pragma unroll
            for (int m = 0; m < 4; ++m) {
                const int r = 16*m + lrow;
                const int rr = (r < NTOK) ? r : 0;
                afr[m] = *reinterpret_cast<const bf16x8*>(o_s + rr*OPITCH + k0);
            }
            bf16x8 bfr[2];
            #pragma unroll
            for (int n = 0; n < 2; ++n) {
                const int c = 32*w + 16*n + lrow;
                if (PRE) {
                    bfr[n] = *reinterpret_cast<const bf16x8*>(wbf + WBF_PROJ + c*DIMC + k0);
                } else {
                    float4 lo = *reinterpret_cast<const float4*>(proj_w + c*DIMC + k0);
                    float4 hi = *reinterpret_cast<const float4*>(proj_w + c*DIMC + k0 + 4);
                    bfr[n] = cvt8(lo, hi);
                }
            }
            #pragma unroll
            for (int m = 0; m < 4; ++m)
                #pragma unroll
                for (int n = 0; n < 2; ++n)
                    pacc[m][n] = __builtin_amdgcn_mfma_f32_16x16x32_bf16(
                                     afr[m], bfr[n], pacc[m][n], 0, 0, 0);
        }

        float* ob = out + (size_t)b * (NTOK * DIMC);
        #pragma unroll
        for (int n = 0; n < 2; ++n) {
            const int c    = 32*w + 16*n + lrow;
            const float bi = proj_b[c];
            #pragma unroll
            for (int m = 0; m < 4; ++m) {
                #pragma unroll
                for (int q = 0; q < 4; ++q) {
                    const int r = 16*m + 4*kgrp + q;
                    if (r < NTOK) ob[r*DIMC + c] = pacc[m][n][q] + bi;
                }
            }
        }
    }
}

extern "C" void kernel_launch(void* const* d_in, const int* in_sizes, int n_in,
                              void* d_out, int out_size, void* d_ws, size_t ws_size,
                              hipStream_t stream) {
    const float* x      = (const float*)d_in[0];
    const float* mask   = (const float*)d_in[1];
    const float* qkv_w  = (const float*)d_in[2];
    const float* qkv_b  = (const float*)d_in[3];
    const float* proj_w = (const float*)d_in[4];
    const float* proj_b = (const float*)d_in[5];
    const float* tbl    = (const float*)d_in[6];
    const int*   ridx   = (const int*)d_in[7];
    float* out = (float*)d_out;

    const int B = in_sizes[0] / (NTOK * DIMC);   // 4096 windows
    const size_t shmem = 49792;                  // bytes (< 64KB: no attr call needed)

    if (ws_size >= WBF_BYTES) {
        short* wbf = (short*)d_ws;
        convert_weights<<<64, 256, 0, stream>>>(qkv_w, proj_w, wbf);
        winattn_fused<true><<<B, 256, shmem, stream>>>(x, mask, qkv_w, qkv_b,
                                                       proj_w, proj_b, tbl, ridx,
                                                       wbf, out);
    } else {
        winattn_fused<false><<<B, 256, shmem, stream>>>(x, mask, qkv_w, qkv_b,
                                                        proj_w, proj_b, tbl, ridx,
                                                        nullptr, out);
    }
}